// Round 1
// baseline (336.745 us; speedup 1.0000x reference)
//
#include <hip/hip_runtime.h>

#define BATCH 16384
#define EMBED 64

// ---------------------------------------------------------------------------
// Kernel 1: sorted seg_ids -> row_start[B+1] (CSR-style offsets).
// row_start[b] = first edge index with seg_ids[e] >= b.  Fully overwrites
// its ws region every call (ws is poisoned 0xAA before each timed launch).
// ---------------------------------------------------------------------------
__global__ void seg_offsets_kernel(const int* __restrict__ seg, int E, int B,
                                   int* __restrict__ row_start) {
    int e = blockIdx.x * blockDim.x + threadIdx.x;
    if (e >= E) return;
    int s1 = seg[e];
    if (e == 0) {
        for (int s = 0; s <= s1; ++s) row_start[s] = 0;
    } else {
        int s0 = seg[e - 1];
        for (int s = s0 + 1; s <= s1; ++s) row_start[s] = e;
    }
    if (e == E - 1) {
        for (int s = s1 + 1; s <= B; ++s) row_start[s] = E;
    }
}

// ---------------------------------------------------------------------------
// Kernel 2: fully fused gather + segment-mean + concat + (x @ w1.T + b1) + relu.
// One wave (64 lanes) per output row. Block = 512 threads = 8 waves.
// LDS: w1 staged at stride 129 (row j at w1s[j*129 + c]) -> GEMM reads hit
// bank (j + c) % 32 across lanes = 2-way aliasing (free on wave64).
// comb[wave][128] holds [self | mean-neigh] per wave.
// Occupancy: 33.0 KB + 4 KB LDS -> 4 blocks/CU -> 32 waves/CU (max).
// grid=1024 * 8 waves = 8192 waves; 16384 rows -> exactly 2 iters/wave, so
// the in-loop __syncthreads has equal trip counts for all waves.
// ---------------------------------------------------------------------------
__global__ __launch_bounds__(512) void social_encoder_fused(
    const int*   __restrict__ nodes,
    const int*   __restrict__ neigh_ids,
    const int*   __restrict__ row_start,
    const float* __restrict__ features,
    const float* __restrict__ w1,
    const float* __restrict__ b1,
    float*       __restrict__ out,
    int B)
{
    __shared__ float w1s[EMBED * 129];       // 64 rows, stride 129 (pad +1)
    __shared__ float comb[8][2 * EMBED];     // per-wave [self(64) | neigh(64)]

    // Stage w1 (64 x 128 row-major) into padded LDS. Consecutive threads write
    // consecutive c within a row -> conflict-free.
    for (int i = threadIdx.x; i < EMBED * 2 * EMBED; i += 512) {
        w1s[(i >> 7) * 129 + (i & 127)] = w1[i];
    }
    __syncthreads();

    const int wave = threadIdx.x >> 6;
    const int lane = threadIdx.x & 63;
    const int q    = lane & 15;   // float4 slot within a 64-float row
    const int sub  = lane >> 4;   // which of 4 concurrent edges
    const float bj = b1[lane];

    for (int b = blockIdx.x * 8 + wave; b < B; b += gridDim.x * 8) {
        const int start = row_start[b];
        const int end   = row_start[b + 1];

        // Gather-accumulate neighbor rows: 4 edges in parallel across sub
        // groups, 16 B/lane float4 loads (256 B coalesced per row), unrolled
        // x2 so each wave keeps 2 independent HBM chains in flight.
        float ax = 0.f, ay = 0.f, az = 0.f, aw = 0.f;
        int e = start + sub;
        for (; e + 4 < end; e += 8) {
            const int r0 = neigh_ids[e];
            const int r1 = neigh_ids[e + 4];
            const float4 v0 = ((const float4*)(features + ((size_t)r0 << 6)))[q];
            const float4 v1 = ((const float4*)(features + ((size_t)r1 << 6)))[q];
            ax += v0.x + v1.x; ay += v0.y + v1.y;
            az += v0.z + v1.z; aw += v0.w + v1.w;
        }
        if (e < end) {
            const int r = neigh_ids[e];
            const float4 v = ((const float4*)(features + ((size_t)r << 6)))[q];
            ax += v.x; ay += v.y; az += v.z; aw += v.w;
        }

        // Reduce the 4 sub-groups (lanes xor 16, xor 32).
        ax += __shfl_xor(ax, 16, 64); ax += __shfl_xor(ax, 32, 64);
        ay += __shfl_xor(ay, 16, 64); ay += __shfl_xor(ay, 32, 64);
        az += __shfl_xor(az, 16, 64); az += __shfl_xor(az, 32, 64);
        aw += __shfl_xor(aw, 16, 64); aw += __shfl_xor(aw, 32, 64);

        const float scale = 1.0f / fmaxf((float)(end - start), 1.0f);

        if (sub == 0) {
            // lanes 0..15: stage self row + mean-neighbor row into LDS.
            const int node = nodes[b];
            const float4 sv = ((const float4*)(features + ((size_t)node << 6)))[q];
            ((float4*)&comb[wave][0])[q] = sv;
            float4 nv;
            nv.x = ax * scale; nv.y = ay * scale;
            nv.z = az * scale; nv.w = aw * scale;
            ((float4*)&comb[wave][EMBED])[q] = nv;
        }
        __syncthreads();  // equal trip count for all waves (B % (grid*8) == 0)

        // out[b][lane] = relu( sum_c comb[c] * w1[lane][c] + b1[lane] )
        float acc = bj;
        const float* wrow = &w1s[lane * 129];
        const float* cb   = comb[wave];
        #pragma unroll
        for (int c = 0; c < 2 * EMBED; c += 4) {
            const float4 cv = *(const float4*)&cb[c];  // broadcast read (free)
            acc += cv.x * wrow[c + 0];
            acc += cv.y * wrow[c + 1];
            acc += cv.z * wrow[c + 2];
            acc += cv.w * wrow[c + 3];
        }
        out[((size_t)b << 6) + lane] = fmaxf(acc, 0.0f);
        // next iteration's comb writes are same-wave only (per-wave region),
        // and same-wave DS ops execute in order -> no second barrier needed.
    }
}

extern "C" void kernel_launch(void* const* d_in, const int* in_sizes, int n_in,
                              void* d_out, int out_size, void* d_ws, size_t ws_size,
                              hipStream_t stream) {
    const int*   nodes     = (const int*)d_in[0];
    const int*   neigh_ids = (const int*)d_in[1];
    const int*   seg_ids   = (const int*)d_in[2];
    const float* features  = (const float*)d_in[3];
    const float* w1        = (const float*)d_in[4];
    const float* b1        = (const float*)d_in[5];
    float*       out       = (float*)d_out;

    const int B = in_sizes[0];      // 16384
    const int E = in_sizes[1];      // 524288

    int* row_start = (int*)d_ws;    // (B+1) ints, fully rewritten every call

    seg_offsets_kernel<<<(E + 255) / 256, 256, 0, stream>>>(seg_ids, E, B, row_start);
    social_encoder_fused<<<1024, 512, 0, stream>>>(nodes, neigh_ids, row_start,
                                                   features, w1, b1, out, B);
}

// Round 4
// 332.510 us; speedup vs baseline: 1.0127x; 1.0127x over previous
//
#include <hip/hip_runtime.h>

#define EMBED 64
#define W1_STRIDE 132   // padded stride (floats): 16B-aligned rows, phase-uniform banks

// ---------------------------------------------------------------------------
// Kernel 1: sorted seg_ids -> row_start[B+1] (CSR offsets). Rewrites its ws
// region fully every call (ws is poisoned 0xAA before each timed launch).
// ---------------------------------------------------------------------------
__global__ void seg_offsets_kernel(const int* __restrict__ seg, int E, int B,
                                   int* __restrict__ row_start) {
    int e = blockIdx.x * blockDim.x + threadIdx.x;
    if (e >= E) return;
    int s1 = seg[e];
    if (e == 0) {
        for (int s = 0; s <= s1; ++s) row_start[s] = 0;
    } else {
        int s0 = seg[e - 1];
        for (int s = s0 + 1; s <= s1; ++s) row_start[s] = e;
    }
    if (e == E - 1) {
        for (int s = s1 + 1; s <= B; ++s) row_start[s] = E;
    }
}

// ---------------------------------------------------------------------------
// Kernel 2: fused gather + segment-mean + concat + (x @ w1.T + b1) + relu.
// One wave per row; 8 waves/block.
//
// CORRECTNESS INVARIANT (round-2/3 bug): every __shfl must execute with all
// 64 lanes active. All loops containing shuffles have WAVE-UNIFORM trip
// counts (bounds derived only from wave-uniform n); ragged coverage is
// handled by predicating the accumulate, never the loop.
//
// Gather: per 64-edge chunk, ONE coalesced neigh_ids load; ids spread via
// __shfl; 4 independent float4 row-loads in flight per 16-lane sub-group.
// comb[wave] is same-wave-only LDS, handed off with __threadfence_block()
// (same-wave DS ops are HW-ordered; fence pins compiler order).
// ---------------------------------------------------------------------------
__global__ __launch_bounds__(512, 8) void social_encoder_fused(
    const int*   __restrict__ nodes,
    const int*   __restrict__ neigh_ids,
    const int*   __restrict__ row_start,
    const float* __restrict__ features,
    const float* __restrict__ w1,
    const float* __restrict__ b1,
    float*       __restrict__ out,
    int B)
{
    __shared__ float w1s[EMBED * W1_STRIDE];  // 33 KB; row j at w1s[j*132+c]
    __shared__ float comb[8][2 * EMBED];      // 4 KB; per-wave [self|mean-neigh]

    for (int i = threadIdx.x; i < EMBED * 2 * EMBED; i += 512)
        w1s[(i >> 7) * W1_STRIDE + (i & 127)] = w1[i];
    __syncthreads();   // only cross-wave barrier in the kernel

    const int wave = threadIdx.x >> 6;
    const int lane = threadIdx.x & 63;
    const int q    = lane & 15;   // float4 slot within a 64-float row
    const int sub  = lane >> 4;   // 4 concurrent edge slots
    const float bj = b1[lane];
    float* cwave = comb[wave];

    for (int b = blockIdx.x * 8 + wave; b < B; b += gridDim.x * 8) {
        const int start = row_start[b];      // wave-uniform
        const int end   = row_start[b + 1];  // wave-uniform
        const int node  = nodes[b];

        // Self row issued early so it overlaps the gather chain.
        const float4 sv = ((const float4*)(features + ((size_t)node << 6)))[q];

        float4 acc = make_float4(0.f, 0.f, 0.f, 0.f);

        for (int chunk = start; chunk < end; chunk += 64) {   // uniform
            const int n = min(64, end - chunk);               // uniform
            int myid = 0;
            if (lane < n) myid = neigh_ids[chunk + lane];     // one coalesced load

            // ---- main: full 16-edge groups, UNIFORM trip count ----
            const int nfull = n & ~15;                        // uniform
            for (int base = 0; base < nfull; base += 16) {
                const int r0 = __shfl(myid, base + sub,      64);
                const int r1 = __shfl(myid, base + sub + 4,  64);
                const int r2 = __shfl(myid, base + sub + 8,  64);
                const int r3 = __shfl(myid, base + sub + 12, 64);
                const float4 v0 = ((const float4*)(features + ((size_t)r0 << 6)))[q];
                const float4 v1 = ((const float4*)(features + ((size_t)r1 << 6)))[q];
                const float4 v2 = ((const float4*)(features + ((size_t)r2 << 6)))[q];
                const float4 v3 = ((const float4*)(features + ((size_t)r3 << 6)))[q];
                acc.x += (v0.x + v1.x) + (v2.x + v3.x);
                acc.y += (v0.y + v1.y) + (v2.y + v3.y);
                acc.z += (v0.z + v1.z) + (v2.z + v3.z);
                acc.w += (v0.w + v1.w) + (v2.w + v3.w);
            }

            // ---- tail: r = n - nfull in [0,15], UNIFORM trip count ----
            const int r = n - nfull;                          // uniform
            const int tmax = (r + 3) >> 2;                    // uniform
            for (int t = 0; t < tmax; ++t) {
                const int src = nfull + sub + 4 * t;          // <= nfull+15 <= 63
                const int rid = __shfl(myid, src, 64);        // all lanes active
                const float4 v = ((const float4*)(features + ((size_t)rid << 6)))[q];
                if (src < n) {   // predicate the ACCUMULATE, not the loop
                    acc.x += v.x; acc.y += v.y; acc.z += v.z; acc.w += v.w;
                }
            }
        }

        // Reduce the 4 sub-groups (full wave active here).
        acc.x += __shfl_xor(acc.x, 16, 64); acc.x += __shfl_xor(acc.x, 32, 64);
        acc.y += __shfl_xor(acc.y, 16, 64); acc.y += __shfl_xor(acc.y, 32, 64);
        acc.z += __shfl_xor(acc.z, 16, 64); acc.z += __shfl_xor(acc.z, 32, 64);
        acc.w += __shfl_xor(acc.w, 16, 64); acc.w += __shfl_xor(acc.w, 32, 64);

        const float scale = 1.0f / fmaxf((float)(end - start), 1.0f);
        float4 nv;
        nv.x = acc.x * scale; nv.y = acc.y * scale;
        nv.z = acc.z * scale; nv.w = acc.w * scale;

        // comb = [self(16 float4) | neigh(16 float4)], slot = lane (0..31).
        const float4 val = (lane < 16) ? sv : nv;
        if (lane < 32) ((float4*)cwave)[lane] = val;

        __threadfence_block();   // real fence; same-wave DS ops are HW-ordered

        float accd = bj;
        const float* wrow = &w1s[lane * W1_STRIDE];
        #pragma unroll 8
        for (int c = 0; c < 2 * EMBED; c += 4) {
            const float4 cv = *(const float4*)&cwave[c];   // broadcast read
            const float4 wv = *(const float4*)&wrow[c];    // ds_read_b128
            accd += cv.x * wv.x + cv.y * wv.y + cv.z * wv.z + cv.w * wv.w;
        }
        out[((size_t)b << 6) + lane] = fmaxf(accd, 0.0f);

        __threadfence_block();   // next iter's comb writes stay after these reads
    }
}

extern "C" void kernel_launch(void* const* d_in, const int* in_sizes, int n_in,
                              void* d_out, int out_size, void* d_ws, size_t ws_size,
                              hipStream_t stream) {
    const int*   nodes     = (const int*)d_in[0];
    const int*   neigh_ids = (const int*)d_in[1];
    const int*   seg_ids   = (const int*)d_in[2];
    const float* features  = (const float*)d_in[3];
    const float* w1        = (const float*)d_in[4];
    const float* b1        = (const float*)d_in[5];
    float*       out       = (float*)d_out;

    const int B = in_sizes[0];      // 16384
    const int E = in_sizes[1];      // 524288

    int* row_start = (int*)d_ws;    // (B+1) ints, fully rewritten every call

    seg_offsets_kernel<<<(E + 255) / 256, 256, 0, stream>>>(seg_ids, E, B, row_start);
    social_encoder_fused<<<1024, 512, 0, stream>>>(nodes, neigh_ids, row_start,
                                                   features, w1, b1, out, B);
}